// Round 3
// baseline (270.516 us; speedup 1.0000x reference)
//
#include <hip/hip_runtime.h>
#include <hip/hip_bf16.h>
#include <float.h>
#include <math.h>

// B=4, S=4096, D=2048, E=64, K=2
#define B_DIM 4
#define S_DIM 4096
#define D_DIM 2048
#define E_DIM 64
#define N_TOK 16384
#define SPLITK 4
#define KSLICE (D_DIM / SPLITK)   // 512
#define MSTEP (KSLICE / 32)       // 16 K-steps of 32
#define TPB 128                   // tokens per main block (4 waves x 32)
#define NMAIN ((N_TOK / TPB) * SPLITK)  // 512 blocks -> 2/CU, 8 waves/CU
#define EPB 16                    // tokens per epilogue block (16 waves x 1)
#define NEPI (N_TOK / EPB)        // 1024
#define GAP_THRESH 1e-3f          // ~500x the split-bf16 logit error

// d_ws byte layout: [0,256K) W-hi plane (ushort), [256K,512K) W-lo plane,
// [512K, 512K+16K) zeroed header (zslot[64], loadp[8][256]), [528K, +16M) partials
#define WS_WLO_B   262144
#define WS_HEAD_B  524288
#define WS_PART_B  540672
#define WS_NEED    (WS_PART_B + (size_t)SPLITK * N_TOK * E_DIM * 4)
#define HEAD_ZSLOT 0              // float idx within header
#define HEAD_LOADP 64

typedef __bf16 bf16x8_t __attribute__((ext_vector_type(8)));
typedef float f32x4_t __attribute__((ext_vector_type(4)));
union U8 { bf16x8_t v; unsigned short u[8]; };

// truncating fp32 -> (bf16 hi, bf16 lo); hi+lo captures ~16 mantissa bits
__device__ __forceinline__ void split2(float f, unsigned short& h, unsigned short& l) {
    unsigned int u = __float_as_uint(f);
    h = (unsigned short)(u >> 16);
    float hf = __uint_as_float(u & 0xFFFF0000u);
    l = (unsigned short)(__float_as_uint(f - hf) >> 16);
}

__global__ __launch_bounds__(256) void wconv(const float* __restrict__ W,
                                             unsigned short* __restrict__ whi,
                                             unsigned short* __restrict__ wlo) {
    const int t = blockIdx.x * 256 + threadIdx.x;    // 32768 threads x 4 elems
    float4 v = *(const float4*)(W + (size_t)t * 4);
    ushort4 h, l;
    split2(v.x, h.x, l.x); split2(v.y, h.y, l.y);
    split2(v.z, h.z, l.z); split2(v.w, h.w, l.w);
    *(ushort4*)(whi + (size_t)t * 4) = h;
    *(ushort4*)(wlo + (size_t)t * 4) = l;
}

// Main GEMM: no LDS, no barriers. Each wave: 32 tokens x 64 experts x KSLICE.
template<bool ATOMIC>
__global__ __launch_bounds__(256, 2) void router_main(
    const float* __restrict__ x,
    const unsigned short* __restrict__ whi, const unsigned short* __restrict__ wlo,
    float* __restrict__ part)   // store: [SPLITK][N_TOK][64] ; atomic: logits [N_TOK][64]
{
    const int tid = threadIdx.x;
    const int lane = tid & 63, wv = tid >> 6;
    const int l15 = lane & 15, quad = lane >> 4;
    const int slice = blockIdx.x & (SPLITK - 1);
    const int grp = blockIdx.x >> 2;
    const int tokBase = grp * TPB + wv * 32;
    const int k0 = slice * KSLICE;

    const float* xb[2];
    xb[0] = x + (size_t)(tokBase + l15) * D_DIM + k0 + quad * 8;
    xb[1] = x + (size_t)(tokBase + 16 + l15) * D_DIM + k0 + quad * 8;

    f32x4_t acc[2][4];
    #pragma unroll
    for (int m = 0; m < 2; ++m)
        #pragma unroll
        for (int t = 0; t < 4; ++t) acc[m][t] = (f32x4_t){0.f, 0.f, 0.f, 0.f};

    float4 xq[2][2], xn[2][2];
    #pragma unroll
    for (int m = 0; m < 2; ++m) {
        xq[m][0] = *(const float4*)(xb[m]);
        xq[m][1] = *(const float4*)(xb[m] + 4);
    }

    #pragma unroll 4
    for (int s = 0; s < MSTEP; ++s) {
        if (s + 1 < MSTEP) {   // prefetch next step's x into regs (no barrier anywhere)
            #pragma unroll
            for (int m = 0; m < 2; ++m) {
                const float* p = xb[m] + (s + 1) * 32;
                xn[m][0] = *(const float4*)(p);
                xn[m][1] = *(const float4*)(p + 4);
            }
        }
        const int kk = k0 + s * 32 + quad * 8;
        bf16x8_t bh[4], bl[4];
        #pragma unroll
        for (int t = 0; t < 4; ++t) {
            const size_t off = (size_t)(t * 16 + l15) * D_DIM + kk;
            bh[t] = *(const bf16x8_t*)(whi + off);   // 16B, L1-shared across waves
            bl[t] = *(const bf16x8_t*)(wlo + off);
        }
        #pragma unroll
        for (int m = 0; m < 2; ++m) {
            float tf[8] = {xq[m][0].x, xq[m][0].y, xq[m][0].z, xq[m][0].w,
                           xq[m][1].x, xq[m][1].y, xq[m][1].z, xq[m][1].w};
            U8 ah, al;
            #pragma unroll
            for (int k = 0; k < 8; ++k) split2(tf[k], ah.u[k], al.u[k]);
            #pragma unroll
            for (int t = 0; t < 4; ++t) {
                acc[m][t] = __builtin_amdgcn_mfma_f32_16x16x32_bf16(ah.v, bh[t], acc[m][t], 0, 0, 0);
                acc[m][t] = __builtin_amdgcn_mfma_f32_16x16x32_bf16(ah.v, bl[t], acc[m][t], 0, 0, 0);
                acc[m][t] = __builtin_amdgcn_mfma_f32_16x16x32_bf16(al.v, bh[t], acc[m][t], 0, 0, 0);
            }
        }
        if (s + 1 < MSTEP) {
            #pragma unroll
            for (int m = 0; m < 2; ++m) { xq[m][0] = xn[m][0]; xq[m][1] = xn[m][1]; }
        }
    }

    // C/D: col(expert-in-tile)=lane&15, row(token-in-tile)=quad*4+r  (verified)
    #pragma unroll
    for (int m = 0; m < 2; ++m)
        #pragma unroll
        for (int t = 0; t < 4; ++t)
            #pragma unroll
            for (int r = 0; r < 4; ++r) {
                const int token = tokBase + m * 16 + quad * 4 + r;
                const int e = t * 16 + l15;
                if (ATOMIC) atomicAdd(&part[(size_t)token * E_DIM + e], acc[m][t][r]);
                else part[((size_t)slice * N_TOK + token) * E_DIM + e] = acc[m][t][r];
            }
}

__device__ __forceinline__ void wave_argmax(float y, float& mv, int& mi) {
    float v = y; int ix = threadIdx.x & 63;
    #pragma unroll
    for (int d = 32; d; d >>= 1) {
        float ov = __shfl_xor(v, d); int oi = __shfl_xor(ix, d);
        if (ov > v || (ov == v && oi < ix)) { v = ov; ix = oi; }
    }
    mv = v; mi = ix;   // all lanes hold the result
}

// Epilogue: one wave per token, lane = expert.
template<bool ATOMIC>
__global__ __launch_bounds__(1024) void router_epi(
    const float* __restrict__ part, const float* __restrict__ x,
    const float* __restrict__ W, const float* __restrict__ gamma,
    const float* __restrict__ beta, const float* __restrict__ temperature,
    float* __restrict__ out_rw, float* __restrict__ out_dp,
    float* __restrict__ zslot, float* __restrict__ loadp)
{
    __shared__ float loadsum[E_DIM];
    __shared__ float zred[EPB];
    const int tid = threadIdx.x;
    const int lane = tid & 63, wv = tid >> 6;
    const int tok = blockIdx.x * EPB + wv;
    if (tid < E_DIM) loadsum[tid] = 0.f;
    __syncthreads();

    // gather logit for (tok, expert=lane)
    float p;
    if (ATOMIC) p = part[(size_t)tok * E_DIM + lane];
    else {
        p = 0.f;
        #pragma unroll
        for (int s = 0; s < SPLITK; ++s) p += part[((size_t)s * N_TOK + tok) * E_DIM + lane];
    }
    // LayerNorm over 64 experts (wave reduce; biased var, matches ref)
    float s1 = p, s2 = p * p;
    #pragma unroll
    for (int d = 32; d; d >>= 1) { s1 += __shfl_xor(s1, d); s2 += __shfl_xor(s2, d); }
    const float mu = s1 * (1.f / 64.f);
    const float var = s2 * (1.f / 64.f) - mu * mu;
    const float rs = rsqrtf(var + 1e-5f);
    const float y = (p - mu) * rs * gamma[lane] + beta[lane];

    float zl = y * y;
    #pragma unroll
    for (int d = 32; d; d >>= 1) zl += __shfl_xor(zl, d);
    if (lane == 0) zred[wv] = zl;

    // top-3 by iterative masked argmax (low-index tie-break = lax.top_k)
    float m0, m1, m2; int i0, i1, i2;
    wave_argmax(y, m0, i0);
    wave_argmax((lane == i0) ? -FLT_MAX : y, m1, i1);
    wave_argmax((lane == i0 || lane == i1) ? -FLT_MAX : y, m2, i2);
    int sa = i0, sb = i1;

    if (m1 - m2 < GAP_THRESH) {   // near-tie: exact fp64 re-rank of 3 candidates
        const float* xr = x + (size_t)tok * D_DIM;
        const int c[3] = {i0, i1, i2};
        double L[3];
        #pragma unroll
        for (int j = 0; j < 3; ++j) {
            const float* wr = W + (size_t)c[j] * D_DIM;
            double a = 0.0;
            for (int i = lane; i < D_DIM; i += 64) a += (double)xr[i] * (double)wr[i];
            #pragma unroll
            for (int d = 32; d; d >>= 1) a += __shfl_xor(a, d);
            L[j] = a;   // all lanes
        }
        double yy[3];
        #pragma unroll
        for (int j = 0; j < 3; ++j)
            yy[j] = (L[j] - (double)mu) * (double)rs * (double)gamma[c[j]] + (double)beta[c[j]];
        bool g01 = (yy[0] > yy[1]) || (yy[0] == yy[1] && c[0] < c[1]);
        bool g02 = (yy[0] > yy[2]) || (yy[0] == yy[2] && c[0] < c[2]);
        bool g12 = (yy[1] > yy[2]) || (yy[1] == yy[2] && c[1] < c[2]);
        if (!g01 && !g02)     { sa = c[1]; sb = c[2]; }
        else if (g01 && !g12) { sa = c[0]; sb = c[2]; }
        else                  { sa = c[0]; sb = c[1]; }
    }

    // temperature softmax
    const float it = 1.f / (temperature[0] + 1e-6f);
    float ev = __expf((y - m0) * it);
    float es = ev;
    #pragma unroll
    for (int d = 32; d; d >>= 1) es += __shfl_xor(es, d);
    const float prob = ev / es;

    out_rw[(size_t)tok * E_DIM + lane] = prob;
    const bool sel = (lane == sa || lane == sb);
    out_dp[(size_t)tok * E_DIM + lane] = sel ? prob : 0.f;
    if (sel) atomicAdd(&loadsum[lane], prob);
    __syncthreads();

    if (tid == 0) {
        float z = 0.f;
        #pragma unroll
        for (int i = 0; i < EPB; ++i) z += zred[i];
        atomicAdd(&zslot[blockIdx.x & 63], z);
    }
    const int b = (blockIdx.x * EPB) >> 12;   // batch (16 | 4096)
    if (tid < E_DIM) atomicAdd(&loadp[(blockIdx.x & 7) * 256 + b * E_DIM + tid], loadsum[tid]);
}

__global__ void router_fin(const float* __restrict__ head, float* __restrict__ out_loss) {
    __shared__ float sv[B_DIM * E_DIM];
    const int tid = threadIdx.x;
    float s = 0.f;
    #pragma unroll
    for (int pl = 0; pl < 8; ++pl) s += head[HEAD_LOADP + pl * 256 + tid];
    sv[tid] = s * (1.f / S_DIM);   // expert_load[b][e]
    __syncthreads();
    if (tid == 0) {
        float t = 0.f;
        for (int i = 0; i < B_DIM * E_DIM; ++i) t += sv[i];
        const float mean = t * (1.f / (B_DIM * E_DIM));
        float ss = 0.f;
        for (int i = 0; i < B_DIM * E_DIM; ++i) { float d = sv[i] - mean; ss += d * d; }
        const float sd = sqrtf(ss * (1.f / (B_DIM * E_DIM - 1)));  // ddof=1
        float z = 0.f;
        for (int i = 0; i < 64; ++i) z += head[HEAD_ZSLOT + i];
        out_loss[0] = 0.001f * (z * (1.f / ((float)N_TOK * E_DIM))) + 0.1f * (sd / mean) * 10.f;
    }
}

extern "C" void kernel_launch(void* const* d_in, const int* in_sizes, int n_in,
                              void* d_out, int out_size, void* d_ws, size_t ws_size,
                              hipStream_t stream) {
    const float* x     = (const float*)d_in[0];
    const float* W     = (const float*)d_in[1];
    const float* gamma = (const float*)d_in[2];
    const float* beta  = (const float*)d_in[3];
    const float* temp  = (const float*)d_in[4];
    float* out  = (float*)d_out;
    float* rw   = out;
    float* dp   = out + (size_t)N_TOK * E_DIM;
    float* loss = out + 2 * (size_t)N_TOK * E_DIM;

    unsigned short* whi = (unsigned short*)d_ws;
    unsigned short* wlo = (unsigned short*)((char*)d_ws + WS_WLO_B);
    float* head = (float*)((char*)d_ws + WS_HEAD_B);
    float* partbuf = (float*)((char*)d_ws + WS_PART_B);
    const bool store_path = (ws_size >= WS_NEED);

    hipMemsetAsync((char*)d_ws + WS_HEAD_B, 0, 16384, stream);
    wconv<<<dim3(128), dim3(256), 0, stream>>>(W, whi, wlo);
    if (store_path) {
        router_main<false><<<dim3(NMAIN), dim3(256), 0, stream>>>(x, whi, wlo, partbuf);
        router_epi<false><<<dim3(NEPI), dim3(1024), 0, stream>>>(
            partbuf, x, W, gamma, beta, temp, rw, dp,
            head + HEAD_ZSLOT, head + HEAD_LOADP);
    } else {
        hipMemsetAsync(rw, 0, (size_t)N_TOK * E_DIM * 4, stream);
        router_main<true><<<dim3(NMAIN), dim3(256), 0, stream>>>(x, whi, wlo, rw);
        router_epi<true><<<dim3(NEPI), dim3(1024), 0, stream>>>(
            rw, x, W, gamma, beta, temp, rw, dp,
            head + HEAD_ZSLOT, head + HEAD_LOADP);
    }
    router_fin<<<dim3(1), dim3(256), 0, stream>>>(head, loss);
}